// Round 1
// baseline (5429.601 us; speedup 1.0000x reference)
//
#include <hip/hip_runtime.h>
#include <math.h>

// mLSTM block, MI355X baseline (round 0).
// Sizes fixed by the reference:
constexpr int BB = 4096;   // batch
constexpr int DD = 2048;   // input size
constexpr int PP = 4096;   // proj size
constexpr int HH = 4096;   // hidden
constexpr int NH = 16;
constexpr int HS = 256;

// Workspace plan: 9 slots of H*B floats (64 MiB each) = 576 MiB, lifetime-aliased.
//   s0 xl | s1 xr | s2 xc -> v -> denom | s3 xs | s4 i_t -> s | s5 f_t
//   s6 o_pre | s7 q | s8 xn -> k

typedef __bf16  bf16x8 __attribute__((ext_vector_type(8)));
typedef float   floatx4 __attribute__((ext_vector_type(4)));

// ---------------------------------------------------------------- LayerNorm
__global__ void ln_kernel(const float* __restrict__ x, const float* __restrict__ g,
                          const float* __restrict__ b, float* __restrict__ xn) {
    int row = blockIdx.x;
    int tid = threadIdx.x;
    const float* xr = x + (long)row * DD;
    float v[8];
    float s1 = 0.f, s2 = 0.f;
#pragma unroll
    for (int i = 0; i < 8; ++i) {
        v[i] = xr[tid + 256 * i];
        s1 += v[i]; s2 += v[i] * v[i];
    }
    for (int off = 32; off > 0; off >>= 1) {
        s1 += __shfl_down(s1, off);
        s2 += __shfl_down(s2, off);
    }
    __shared__ float r1[4], r2[4];
    if ((tid & 63) == 0) { r1[tid >> 6] = s1; r2[tid >> 6] = s2; }
    __syncthreads();
    float t1 = r1[0] + r1[1] + r1[2] + r1[3];
    float t2 = r2[0] + r2[1] + r2[2] + r2[3];
    float mu  = t1 * (1.f / DD);
    float var = t2 * (1.f / DD) - mu * mu;
    float inv = rsqrtf(var + 1e-5f);
    float* xo = xn + (long)row * DD;
#pragma unroll
    for (int i = 0; i < 8; ++i) {
        int c = tid + 256 * i;
        xo[c] = (v[i] - mu) * inv * g[c] + b[c];
    }
}

// ---------------------------------------------------------------- conv + silu
__global__ void conv_silu_kernel(const float* __restrict__ xl, const float* __restrict__ w,
                                 const float* __restrict__ cb, float* __restrict__ xc) {
    long i = (long)blockIdx.x * 256 + threadIdx.x;   // over B*P
    int p = (int)(i & (PP - 1));
    const float* base = xl + (i - p);
    float acc = cb[0];
#pragma unroll
    for (int j = 0; j < 4; ++j) {
        int pp = p - 3 + j;
        if (pp >= 0) acc = fmaf(w[j], base[pp], acc);
    }
    xc[i] = acc / (1.f + expf(-acc));
}

// ---------------------------------------------------------------- gates
__global__ void gates_kernel(const float* __restrict__ it_, const float* __restrict__ ft_,
                             const float* __restrict__ mp, const float* __restrict__ cp,
                             const float* __restrict__ np, const float* __restrict__ kk,
                             const float* __restrict__ vv,
                             float* __restrict__ c_out, float* __restrict__ n_out,
                             float* __restrict__ m_out) {
    long i = (long)blockIdx.x * 256 + threadIdx.x;   // over B*H
    float it = it_[i], ft = ft_[i];
    float fm = ft + mp[i];
    float mt = fmaxf(fm, it);
    float ig = expf(it - mt);
    float fg = expf(fm - mt);
    float ks = kk[i] * 0.0625f;                       // 1/sqrt(HS)
    c_out[i] = fg * cp[i] + ig * (vv[i] * ks);
    n_out[i] = fg * np[i] + ig * ks;
    m_out[i] = mt;
}

// ---------------------------------------------------------------- h_t + GroupNorm + mix
__global__ void hgn_kernel(const float* __restrict__ o_pre, const float* __restrict__ ct,
                           const float* __restrict__ qm, const float* __restrict__ den,
                           const float* __restrict__ xs, const float* __restrict__ xr,
                           const float* __restrict__ gg, const float* __restrict__ gb,
                           float* __restrict__ h_out, float* __restrict__ s_out) {
    int blk = blockIdx.x;            // b*NH + head
    int b = blk >> 4, hd = blk & 15;
    int c = threadIdx.x;             // 0..255 == HS
    int gcol = hd * HS + c;
    long idx = (long)b * HH + gcol;
    float o  = 1.f / (1.f + expf(-o_pre[idx]));
    float ht = o * ct[idx] * qm[idx] / fmaxf(fabsf(den[idx]), 1.f);
    h_out[idx] = ht;
    float s1 = ht, s2 = ht * ht;
    for (int off = 32; off > 0; off >>= 1) {
        s1 += __shfl_down(s1, off);
        s2 += __shfl_down(s2, off);
    }
    __shared__ float r1[4], r2[4];
    if ((c & 63) == 0) { r1[c >> 6] = s1; r2[c >> 6] = s2; }
    __syncthreads();
    float t1 = r1[0] + r1[1] + r1[2] + r1[3];
    float t2 = r2[0] + r2[1] + r2[2] + r2[3];
    float mu  = t1 * (1.f / HS);
    float var = t2 * (1.f / HS) - mu * mu;
    float gn  = (ht - mu) * rsqrtf(var + 1e-5f) * gg[gcol] + gb[gcol];
    float xrv = xr[idx];
    float sil = xrv / (1.f + expf(-xrv));
    s_out[idx] = (gn + xs[idx]) * sil;
}

// ---------------------------------------------------------------- GEMM (bf16 MFMA, fp32 IO)
// C[m,n] = sum_k A*B + bias[n] (+ res[m,n]).
// TA=false: A is [M,K] row-major.  TA=true: A is [K,M] row-major (C = A^T B).
// B is always [K,N] row-major. Converts fp32->bf16 during LDS staging.
// 128x128 tile, BK=32, 256 threads = 4 waves (2x2 of 64x64), mfma_f32_16x16x32_bf16.
template<bool TA>
__global__ __launch_bounds__(256)
void gemm_bf16(const float* __restrict__ A, int lda, long sAz,
               const float* __restrict__ Bm, int ldb, long sBz,
               const float* __restrict__ bias, int sbz,
               const float* __restrict__ res,
               float* __restrict__ C, int ldc, long sCz,
               int K) {
    const int tid = threadIdx.x;
    const int m0 = blockIdx.y * 128;
    const int n0 = blockIdx.x * 128;
    const int z  = blockIdx.z;
    A  += (long)z * sAz;
    Bm += (long)z * sBz;
    C  += (long)z * sCz;
    if (bias) bias += (long)z * sbz;

    __shared__ __bf16 As[128][40];   // [m][k], +8 pad: 16B-aligned b128 frag reads
    __shared__ __bf16 Bs[128][40];   // [n][k]

    floatx4 acc[4][4] = {};

    const int lane = tid & 63, wave = tid >> 6;
    const int wm = (wave >> 1) * 64, wn = (wave & 1) * 64;
    const int lr = lane & 15, qd = lane >> 4;

    for (int k0 = 0; k0 < K; k0 += 32) {
        if (!TA) {
            // A-tile 128(m) x 32(k): thread loads 4x float4 along k
            int r = tid >> 3, cc = (tid & 7) * 4;
#pragma unroll
            for (int s = 0; s < 4; ++s) {
                const float4 f = *reinterpret_cast<const float4*>(
                    &A[(long)(m0 + r + 32 * s) * lda + k0 + cc]);
                __bf16* d = &As[r + 32 * s][cc];
                d[0] = (__bf16)f.x; d[1] = (__bf16)f.y; d[2] = (__bf16)f.z; d[3] = (__bf16)f.w;
            }
        } else {
            // A-tile 32(k) x 128(m): transpose into As[m][k]
            int kr = tid >> 5, mm = (tid & 31) * 4;
#pragma unroll
            for (int s = 0; s < 4; ++s) {
                const float4 f = *reinterpret_cast<const float4*>(
                    &A[(long)(k0 + kr + 8 * s) * lda + m0 + mm]);
                As[mm + 0][kr + 8 * s] = (__bf16)f.x;
                As[mm + 1][kr + 8 * s] = (__bf16)f.y;
                As[mm + 2][kr + 8 * s] = (__bf16)f.z;
                As[mm + 3][kr + 8 * s] = (__bf16)f.w;
            }
        }
        {
            // B-tile 32(k) x 128(n): transpose into Bs[n][k]
            int kr = tid >> 5, nn = (tid & 31) * 4;
#pragma unroll
            for (int s = 0; s < 4; ++s) {
                const float4 f = *reinterpret_cast<const float4*>(
                    &Bm[(long)(k0 + kr + 8 * s) * ldb + n0 + nn]);
                Bs[nn + 0][kr + 8 * s] = (__bf16)f.x;
                Bs[nn + 1][kr + 8 * s] = (__bf16)f.y;
                Bs[nn + 2][kr + 8 * s] = (__bf16)f.z;
                Bs[nn + 3][kr + 8 * s] = (__bf16)f.w;
            }
        }
        __syncthreads();

        bf16x8 af[4], bf[4];
#pragma unroll
        for (int i = 0; i < 4; ++i)
            af[i] = *reinterpret_cast<const bf16x8*>(&As[wm + i * 16 + lr][qd * 8]);
#pragma unroll
        for (int j = 0; j < 4; ++j)
            bf[j] = *reinterpret_cast<const bf16x8*>(&Bs[wn + j * 16 + lr][qd * 8]);
#pragma unroll
        for (int i = 0; i < 4; ++i)
#pragma unroll
            for (int j = 0; j < 4; ++j)
                acc[i][j] = __builtin_amdgcn_mfma_f32_16x16x32_bf16(af[i], bf[j], acc[i][j], 0, 0, 0);
        __syncthreads();
    }

    // epilogue: D row = (lane>>4)*4 + reg, col = lane&15 (verified m89 layout)
#pragma unroll
    for (int i = 0; i < 4; ++i) {
        int rowb = m0 + wm + i * 16 + qd * 4;
#pragma unroll
        for (int j = 0; j < 4; ++j) {
            int col = n0 + wn + j * 16 + lr;
            float bi = bias ? bias[col] : 0.f;
#pragma unroll
            for (int r = 0; r < 4; ++r) {
                long gi = (long)(rowb + r) * ldc + col;
                float v = acc[i][j][r] + bi;
                if (res) v += res[gi];
                C[gi] = v;
            }
        }
    }
}

// ---------------------------------------------------------------- launch
extern "C" void kernel_launch(void* const* d_in, const int* in_sizes, int n_in,
                              void* d_out, int out_size, void* d_ws, size_t ws_size,
                              hipStream_t stream) {
    const float* x      = (const float*)d_in[0];
    // d_in[1] = h_prev (unused by the reference math)
    const float* c_prev = (const float*)d_in[2];
    const float* n_prev = (const float*)d_in[3];
    const float* m_prev = (const float*)d_in[4];
    const float* ln_g   = (const float*)d_in[5];
    const float* ln_b   = (const float*)d_in[6];
    const float* W_upL  = (const float*)d_in[7];
    const float* b_upL  = (const float*)d_in[8];
    const float* W_upR  = (const float*)d_in[9];
    const float* b_upR  = (const float*)d_in[10];
    const float* conv_w = (const float*)d_in[11];
    const float* conv_b = (const float*)d_in[12];
    const float* W_skip = (const float*)d_in[13];
    const float* b_skip = (const float*)d_in[14];
    const float* Wq_w   = (const float*)d_in[15];
    const float* Wq_b   = (const float*)d_in[16];
    const float* Wk_w   = (const float*)d_in[17];
    const float* Wk_b   = (const float*)d_in[18];
    const float* Wv_w   = (const float*)d_in[19];
    const float* Wv_b   = (const float*)d_in[20];
    const float* Wi_w   = (const float*)d_in[21];
    const float* Wi_b   = (const float*)d_in[22];
    const float* Wf_w   = (const float*)d_in[23];
    const float* Wf_b   = (const float*)d_in[24];
    const float* Wo_w   = (const float*)d_in[25];
    const float* Wo_b   = (const float*)d_in[26];
    const float* gn_g   = (const float*)d_in[27];
    const float* gn_b   = (const float*)d_in[28];
    const float* W_down = (const float*)d_in[29];
    const float* b_down = (const float*)d_in[30];

    float* out0  = (float*)d_out;                       // [B, D]
    float* h_out = out0  + (long)BB * DD;               // [B, H]
    float* c_out = h_out + (long)BB * HH;
    float* n_out = c_out + (long)BB * HH;
    float* m_out = n_out + (long)BB * HH;

    float* ws = (float*)d_ws;
    const long SLOT = (long)BB * HH;                    // 16,777,216 floats
    float* xl    = ws + 0 * SLOT;
    float* xr    = ws + 1 * SLOT;
    float* xc    = ws + 2 * SLOT;   // later: v, then denom
    float* xs    = ws + 3 * SLOT;
    float* it    = ws + 4 * SLOT;   // later: s
    float* ft    = ws + 5 * SLOT;
    float* opre  = ws + 6 * SLOT;
    float* qbuf  = ws + 7 * SLOT;
    float* xn    = ws + 8 * SLOT;   // later: k
    float* vbuf  = xc;
    float* denom = xc;
    float* sbuf  = it;
    float* kbuf  = xn;

    dim3 blk(256);

    // 1. LayerNorm
    ln_kernel<<<BB, blk, 0, stream>>>(x, ln_g, ln_b, xn);

    // 2. x_left = xn @ W_upL + b_upL   [B,P]
    gemm_bf16<false><<<dim3(PP / 128, BB / 128, 1), blk, 0, stream>>>(
        xn, DD, 0, W_upL, PP, 0, b_upL, 0, nullptr, xl, PP, 0, DD);
    // 3. x_right = xn @ W_upR + b_upR  [B,H]
    gemm_bf16<false><<<dim3(HH / 128, BB / 128, 1), blk, 0, stream>>>(
        xn, DD, 0, W_upR, HH, 0, b_upR, 0, nullptr, xr, HH, 0, DD);

    // 4. causal conv(4) + silu
    conv_silu_kernel<<<(long)BB * PP / 256, blk, 0, stream>>>(xl, conv_w, conv_b, xc);

    // 5. x_skip = xc @ W_skip + b_skip
    gemm_bf16<false><<<dim3(HH / 128, BB / 128, 1), blk, 0, stream>>>(
        xc, PP, 0, W_skip, HH, 0, b_skip, 0, nullptr, xs, HH, 0, PP);
    // 6. i_tilde = xc @ Wi + bi
    gemm_bf16<false><<<dim3(HH / 128, BB / 128, 1), blk, 0, stream>>>(
        xc, PP, 0, Wi_w, HH, 0, Wi_b, 0, nullptr, it, HH, 0, PP);
    // 7. f_tilde = xc @ Wf + bf
    gemm_bf16<false><<<dim3(HH / 128, BB / 128, 1), blk, 0, stream>>>(
        xc, PP, 0, Wf_w, HH, 0, Wf_b, 0, nullptr, ft, HH, 0, PP);
    // 8. o_pre = xl @ Wo + bo
    gemm_bf16<false><<<dim3(HH / 128, BB / 128, 1), blk, 0, stream>>>(
        xl, PP, 0, Wo_w, HH, 0, Wo_b, 0, nullptr, opre, HH, 0, PP);

    // 9. q = blockdiag(xc, Wq) + bq   (per-head GEMMs via blockIdx.z)
    gemm_bf16<false><<<dim3(HS / 128, BB / 128, NH), blk, 0, stream>>>(
        xc, PP, HS, Wq_w, HS, (long)HS * HS, Wq_b, HS, nullptr, qbuf, HH, HS, HS);
    // 10. k_raw (scaled by 1/16 later in gates)
    gemm_bf16<false><<<dim3(HS / 128, BB / 128, NH), blk, 0, stream>>>(
        xc, PP, HS, Wk_w, HS, (long)HS * HS, Wk_b, HS, nullptr, kbuf, HH, HS, HS);
    // 11. v = blockdiag(xl, Wv) + bv
    gemm_bf16<false><<<dim3(HS / 128, BB / 128, NH), blk, 0, stream>>>(
        xl, PP, HS, Wv_w, HS, (long)HS * HS, Wv_b, HS, nullptr, vbuf, HH, HS, HS);

    // 12. gates -> c_t, n_t, m_t straight into d_out
    gates_kernel<<<(long)BB * HH / 256, blk, 0, stream>>>(
        it, ft, m_prev, c_prev, n_prev, kbuf, vbuf, c_out, n_out, m_out);

    // 13. denom_in = n_t^T @ q   [H,H]  (TN GEMM, reads n_t from d_out)
    gemm_bf16<true><<<dim3(HH / 128, HH / 128, 1), blk, 0, stream>>>(
        n_out, HH, 0, qbuf, HH, 0, nullptr, 0, nullptr, denom, HH, 0, BB);

    // 14. h_t, GroupNorm, s = (gn + x_skip) * silu(x_right)
    hgn_kernel<<<BB * NH, blk, 0, stream>>>(
        opre, c_out, qbuf, denom, xs, xr, gn_g, gn_b, h_out, sbuf);

    // 15. out = s @ W_down + b_down + x  -> d_out[0]
    gemm_bf16<false><<<dim3(DD / 128, BB / 128, 1), blk, 0, stream>>>(
        sbuf, HH, 0, W_down, DD, 0, b_down, 0, x, out0, DD, 0, HH);
}